// Round 5
// baseline (1975.068 us; speedup 1.0000x reference)
//
#include <hip/hip_runtime.h>
#include <cstdint>
#include <cstddef>

#define NLAYERS 3
#define NN      512
#define DIN     4
#define MTILE   64            // batch rows per workgroup
#define KAUG    544           // 512 (H/T) + 4 (X) + 1 (bias one) + 27 zero pad
#define LDA     552           // LDS row stride in bf16 elems
#define WELEMS  (NN * KAUG)   // one weight matrix, bf16 elems
#define LDS_BYTES (2 * MTILE * LDA * 2)
#define NTHREADS 512          // 8 waves, one 64-col block per wave

typedef __attribute__((ext_vector_type(8))) short short8;   // 8 x bf16 (4 VGPRs)
typedef __attribute__((ext_vector_type(4))) float f32x4;    // MFMA accumulator

__device__ __forceinline__ short f2bf(float f) {
    union { float f; uint32_t u; } v; v.f = f;
    uint32_t r = v.u + 0x7fffu + ((v.u >> 16) & 1u);   // RNE
    return (short)(r >> 16);
}
__device__ __forceinline__ float bf2f(short s) {
    union { uint32_t u; float f; } v; v.u = ((uint32_t)(uint16_t)s) << 16;
    return v.f;
}
__device__ __forceinline__ float sig_(float x)  { return 1.0f / (1.0f + __expf(-x)); }
__device__ __forceinline__ float tanh_(float x) { return 1.0f - 2.0f / (1.0f + __expf(2.0f * x)); }
__device__ __forceinline__ float silu_(float x) { return x / (1.0f + __expf(-x)); }

// ---------------- prep: bf16 weights in ws, two regions ---------------------------------
// Region A (fused F/U/O1, per layer): elem ws[L*3*WELEMS + (n*3 + t)*KAUG + kk], t=0:F,1:U,2:O1
//   kk<512 -> U_t[kk][n]; 512..515 -> W_t[kk-512][n]; 516 -> b_t[n]; else 0.
// Region B (O2, per layer):          elem ws[9*WELEMS + L*WELEMS + n*KAUG + kk]
//   kk<512 -> Wo2[kk][n]; 516 -> bo2[n]; else 0.
__global__ void prep_kernel(const float* __restrict__ Wf,  const float* __restrict__ Uf,  const float* __restrict__ bf,
                            const float* __restrict__ Wu,  const float* __restrict__ Uu,  const float* __restrict__ bu,
                            const float* __restrict__ Wo1, const float* __restrict__ Uo1, const float* __restrict__ bo1,
                            const float* __restrict__ Wo2, const float* __restrict__ bo2,
                            short* __restrict__ ws) {
    int idx = blockIdx.x * 256 + threadIdx.x;
    if (idx >= 12 * WELEMS) return;
    int layer, t, n, kk;
    if (idx < 9 * WELEMS) {
        layer   = idx / (3 * WELEMS);
        int rem = idx - layer * 3 * WELEMS;
        n       = rem / (3 * KAUG);
        int r2  = rem - n * 3 * KAUG;
        t       = r2 / KAUG;
        kk      = r2 - t * KAUG;
    } else {
        int i2  = idx - 9 * WELEMS;
        layer   = i2 / WELEMS;
        int rem = i2 - layer * WELEMS;
        n       = rem / KAUG;
        kk      = rem - n * KAUG;
        t       = 3;
    }
    const float* U; const float* W; const float* b;
    switch (t) {
        case 0:  U = Uf;  W = Wf;      b = bf;  break;
        case 1:  U = Uu;  W = Wu;      b = bu;  break;
        case 2:  U = Uo1; W = Wo1;     b = bo1; break;
        default: U = Wo2; W = nullptr; b = bo2; break;
    }
    float val = 0.0f;
    if (kk < NN)             val = U[layer * NN * NN + kk * NN + n];
    else if (kk < NN + DIN)  val = W ? W[layer * DIN * NN + (kk - NN) * NN + n] : 0.0f;
    else if (kk == NN + DIN) val = b[layer * NN + n];
    ws[idx] = f2bf(val);
}

// ---- fused triple 64x64 @ K=544: A (LDS) read ONCE for F,U,O1; B interleaved layout ----
// Per nt-block one pointer; F/U/O1 at byte offsets +0 / +1088 / +2176 (13-bit imm).
// k-step double-buffered (R2's proven shape).
__device__ __forceinline__ void mm3(const short* __restrict__ Asrc, const short* __restrict__ fused,
                                    int n0, int l16, int quad,
                                    f32x4 (&aF)[4][4], f32x4 (&aU)[4][4], f32x4 (&aO)[4][4]) {
#pragma unroll
    for (int mt = 0; mt < 4; ++mt)
#pragma unroll
        for (int nt = 0; nt < 4; ++nt) {
            aF[mt][nt] = f32x4{0.f, 0.f, 0.f, 0.f};
            aU[mt][nt] = f32x4{0.f, 0.f, 0.f, 0.f};
            aO[mt][nt] = f32x4{0.f, 0.f, 0.f, 0.f};
        }
    const short* aP = Asrc + l16 * LDA + quad * 8;
    const short* p0 = fused + (size_t)(n0 +  0 + l16) * 3 * KAUG + quad * 8;
    const short* p1 = fused + (size_t)(n0 + 16 + l16) * 3 * KAUG + quad * 8;
    const short* p2 = fused + (size_t)(n0 + 32 + l16) * 3 * KAUG + quad * 8;
    const short* p3 = fused + (size_t)(n0 + 48 + l16) * 3 * KAUG + quad * 8;

    short8 avA[4], avB[4];
    short8 bFA[4], bUA[4], bOA[4], bFB[4], bUB[4], bOB[4];

#define LD_A(dst, off) { \
    dst[0] = *(const short8*)(aP + 0 * 16 * LDA + (off)); \
    dst[1] = *(const short8*)(aP + 1 * 16 * LDA + (off)); \
    dst[2] = *(const short8*)(aP + 2 * 16 * LDA + (off)); \
    dst[3] = *(const short8*)(aP + 3 * 16 * LDA + (off)); }
#define LD_B(dF, dU, dO, off) { \
    dF[0] = *(const short8*)(p0 + (off));             dU[0] = *(const short8*)(p0 + KAUG + (off)); \
    dO[0] = *(const short8*)(p0 + 2 * KAUG + (off)); \
    dF[1] = *(const short8*)(p1 + (off));             dU[1] = *(const short8*)(p1 + KAUG + (off)); \
    dO[1] = *(const short8*)(p1 + 2 * KAUG + (off)); \
    dF[2] = *(const short8*)(p2 + (off));             dU[2] = *(const short8*)(p2 + KAUG + (off)); \
    dO[2] = *(const short8*)(p2 + 2 * KAUG + (off)); \
    dF[3] = *(const short8*)(p3 + (off));             dU[3] = *(const short8*)(p3 + KAUG + (off)); \
    dO[3] = *(const short8*)(p3 + 2 * KAUG + (off)); }
#define MFMA3(av, bF, bU, bO) { \
    _Pragma("unroll") \
    for (int mt = 0; mt < 4; ++mt) { \
        _Pragma("unroll") \
        for (int nt = 0; nt < 4; ++nt) { \
            aF[mt][nt] = __builtin_amdgcn_mfma_f32_16x16x32_bf16(av[mt], bF[nt], aF[mt][nt], 0, 0, 0); \
            aU[mt][nt] = __builtin_amdgcn_mfma_f32_16x16x32_bf16(av[mt], bU[nt], aU[mt][nt], 0, 0, 0); \
            aO[mt][nt] = __builtin_amdgcn_mfma_f32_16x16x32_bf16(av[mt], bO[nt], aO[mt][nt], 0, 0, 0); \
        } } }

    LD_A(avA, 0);
    LD_B(bFA, bUA, bOA, 0);
#pragma unroll 1
    for (int i = 0; i < 8; ++i) {
        LD_A(avB, 32);
        LD_B(bFB, bUB, bOB, 32);
        MFMA3(avA, bFA, bUA, bOA);
        LD_A(avA, 64);
        LD_B(bFA, bUA, bOA, 64);
        MFMA3(avB, bFB, bUB, bOB);
        aP += 64; p0 += 64; p1 += 64; p2 += 64; p3 += 64;
    }
    MFMA3(avA, bFA, bUA, bOA);
#undef LD_A
#undef LD_B
#undef MFMA3
}

// single 64x64 @ K=544 (phase B): R2's proven structure
__device__ __forceinline__ void mm1(const short* __restrict__ Asrc, const short* __restrict__ Bt,
                                    int n0, int l16, int quad, f32x4 (&acc)[4][4]) {
#pragma unroll
    for (int mt = 0; mt < 4; ++mt)
#pragma unroll
        for (int nt = 0; nt < 4; ++nt) acc[mt][nt] = f32x4{0.f, 0.f, 0.f, 0.f};
    const short* aP = Asrc + l16 * LDA + quad * 8;
    const short* q0 = Bt + (size_t)(n0 +  0 + l16) * KAUG + quad * 8;
    const short* q1 = Bt + (size_t)(n0 + 16 + l16) * KAUG + quad * 8;
    const short* q2 = Bt + (size_t)(n0 + 32 + l16) * KAUG + quad * 8;
    const short* q3 = Bt + (size_t)(n0 + 48 + l16) * KAUG + quad * 8;
    short8 aA[4], bA[4], aB[4], bB[4];
#define LD_A1(dst, off) { \
    dst[0] = *(const short8*)(aP + 0 * 16 * LDA + (off)); \
    dst[1] = *(const short8*)(aP + 1 * 16 * LDA + (off)); \
    dst[2] = *(const short8*)(aP + 2 * 16 * LDA + (off)); \
    dst[3] = *(const short8*)(aP + 3 * 16 * LDA + (off)); }
#define LD_B1(dst, off) { \
    dst[0] = *(const short8*)(q0 + (off)); dst[1] = *(const short8*)(q1 + (off)); \
    dst[2] = *(const short8*)(q2 + (off)); dst[3] = *(const short8*)(q3 + (off)); }
#define MFMA1(av, bv) { \
    _Pragma("unroll") \
    for (int mt = 0; mt < 4; ++mt) { \
        _Pragma("unroll") \
        for (int nt = 0; nt < 4; ++nt) \
            acc[mt][nt] = __builtin_amdgcn_mfma_f32_16x16x32_bf16(av[mt], bv[nt], acc[mt][nt], 0, 0, 0); } }
    LD_A1(aA, 0); LD_B1(bA, 0);
#pragma unroll 1
    for (int i = 0; i < 8; ++i) {
        LD_A1(aB, 32); LD_B1(bB, 32);
        MFMA1(aA, bA);
        LD_A1(aA, 64); LD_B1(bA, 64);
        MFMA1(aB, bB);
        aP += 64; q0 += 64; q1 += 64; q2 += 64; q3 += 64;
    }
    MFMA1(aA, bA);
#undef LD_A1
#undef LD_B1
#undef MFMA1
}

// ---------------- fused DGM kernel: one 8-wave workgroup = 64 batch rows -----------------
__global__ void __launch_bounds__(NTHREADS, 2)
dgm_kernel(const float* __restrict__ X, const float* __restrict__ W_in, const float* __restrict__ b_in,
           const float* __restrict__ W_out, const float* __restrict__ b_out,
           const short* __restrict__ wmats, float* __restrict__ out) {
    extern __shared__ short lds[];
    short* Hb = lds;                 // [MTILE][LDA]  bf16, cols 512..516 = [X|1]
    short* Tb = lds + MTILE * LDA;   // [MTILE][LDA]  bf16, augmentation (0,0,0,0,1)

    const int tid  = threadIdx.x;
    const int lane = tid & 63;
    const int wv   = __builtin_amdgcn_readfirstlane(tid >> 6);  // wave id, SGPR-uniform
    const int l16  = lane & 15;
    const int quad = lane >> 4;
    const int n0   = wv * 64;        // this wave's 64-column block
    const int rbase = blockIdx.x * MTILE;

    // ---- H = silu(X @ W_in + b_in), plus one-time augmentation columns ----
#pragma unroll 4
    for (int j = 0; j < (MTILE * NN) / NTHREADS; ++j) {
        int idx = tid + j * NTHREADS;
        int r = idx >> 9;
        int c = idx & (NN - 1);
        const float* xr = X + (size_t)(rbase + r) * DIN;
        float v = b_in[c];
#pragma unroll
        for (int k = 0; k < DIN; ++k) v += xr[k] * W_in[k * NN + c];
        Hb[r * LDA + c] = f2bf(silu_(v));
    }
    if (tid < MTILE) {
        int r = tid;
        const float* xr = X + (size_t)(rbase + r) * DIN;
#pragma unroll
        for (int k = 0; k < DIN; ++k) {
            Hb[r * LDA + NN + k] = f2bf(xr[k]);
            Tb[r * LDA + NN + k] = 0;
        }
        Hb[r * LDA + NN + DIN] = f2bf(1.0f);
        Tb[r * LDA + NN + DIN] = f2bf(1.0f);
        for (int k = NN + DIN + 1; k < KAUG; ++k) {
            Hb[r * LDA + k] = 0;
            Tb[r * LDA + k] = 0;
        }
    }
    __syncthreads();

    uint32_t Fpack[32];   // sigmoid(F) for this wave's 64x64 tile, packed bf16 pairs

    for (int layer = 0; layer < NLAYERS; ++layer) {
        const short* wFUO = wmats + (size_t)layer * 3 * WELEMS;
        const short* wO2  = wmats + (size_t)9 * WELEMS + (size_t)layer * WELEMS;

        // ---- Phase A: one fused K-pass -> F, U, O1; T = sig(U)*tanh(O1) -> Tb ----
        {
            f32x4 aF[4][4], aU[4][4], aO[4][4];
            mm3(Hb, wFUO, n0, l16, quad, aF, aU, aO);
#pragma unroll
            for (int mt = 0; mt < 4; ++mt)
#pragma unroll
                for (int nt = 0; nt < 4; ++nt)
#pragma unroll
                    for (int rg = 0; rg < 4; ++rg) {
                        int row = mt * 16 + quad * 4 + rg;
                        int col = n0 + nt * 16 + l16;
                        float uu = sig_(aU[mt][nt][rg]);
                        float oo = tanh_(aO[mt][nt][rg]);
                        Tb[row * LDA + col] = f2bf(uu * oo);
                    }
#pragma unroll
            for (int mt = 0; mt < 4; ++mt)
#pragma unroll
                for (int nt = 0; nt < 4; ++nt)
#pragma unroll
                    for (int rp = 0; rp < 2; ++rp) {
                        uint32_t lo = (uint16_t)f2bf(sig_(aF[mt][nt][2 * rp + 0]));
                        uint32_t hi = (uint16_t)f2bf(sig_(aF[mt][nt][2 * rp + 1]));
                        Fpack[mt * 8 + nt * 2 + rp] = lo | (hi << 16);
                    }
        }
        __syncthreads();   // Tb complete everywhere; Hb A-reads done

        // ---- Phase B: O2 = silu(T @ Wo2 + bo2); H = F*H + O2 (own tile only) ----
        {
            f32x4 aO2[4][4];
            mm1(Tb, wO2, n0, l16, quad, aO2);
#pragma unroll
            for (int mt = 0; mt < 4; ++mt)
#pragma unroll
                for (int nt = 0; nt < 4; ++nt)
#pragma unroll
                    for (int rg = 0; rg < 4; ++rg) {
                        uint32_t fp = Fpack[mt * 8 + nt * 2 + (rg >> 1)];
                        float f = bf2f((short)(uint16_t)((rg & 1) ? (fp >> 16) : (fp & 0xffffu)));
                        int row = mt * 16 + quad * 4 + rg;
                        int col = n0 + nt * 16 + l16;
                        float hold = bf2f(Hb[row * LDA + col]);
                        float o2 = silu_(aO2[mt][nt][rg]);
                        Hb[row * LDA + col] = f2bf(f * hold + o2);
                    }
        }
        __syncthreads();   // Hb fully updated before next layer reads all of it
    }

    // ---- out = silu(H @ W_out + b_out) ----
    {
        const int r = tid >> 3, q = tid & 7;
        const int c0 = q * (NN / 8);
        float p = 0.0f;
        for (int c = c0; c < c0 + NN / 8; ++c)
            p += bf2f(Hb[r * LDA + c]) * W_out[c];
        float* red = (float*)Tb;     // Tb is free now
        red[tid] = p;
        __syncthreads();
        if (q == 0) {
            float s = b_out[0];
#pragma unroll
            for (int i = 0; i < 8; ++i) s += red[r * 8 + i];
            out[rbase + r] = silu_(s);
        }
    }
}

extern "C" void kernel_launch(void* const* d_in, const int* in_sizes, int n_in,
                              void* d_out, int out_size, void* d_ws, size_t ws_size,
                              hipStream_t stream) {
    const float* X     = (const float*)d_in[0];
    const float* W_in  = (const float*)d_in[1];
    const float* b_in  = (const float*)d_in[2];
    const float* Wf    = (const float*)d_in[3];
    const float* Uf    = (const float*)d_in[4];
    const float* bf    = (const float*)d_in[5];
    const float* Wu    = (const float*)d_in[6];
    const float* Uu    = (const float*)d_in[7];
    const float* bu    = (const float*)d_in[8];
    const float* Wo1   = (const float*)d_in[9];
    const float* Uo1   = (const float*)d_in[10];
    const float* bo1   = (const float*)d_in[11];
    const float* Wo2   = (const float*)d_in[12];
    const float* bo2   = (const float*)d_in[13];
    const float* W_out = (const float*)d_in[14];
    const float* b_out = (const float*)d_in[15];
    float* out = (float*)d_out;
    short* ws  = (short*)d_ws;       // needs 12*512*544*2 = 6.7 MB

    const int B = in_sizes[0] / DIN;

    prep_kernel<<<(12 * WELEMS + 255) / 256, 256, 0, stream>>>(
        Wf, Uf, bf, Wu, Uu, bu, Wo1, Uo1, bo1, Wo2, bo2, ws);

    hipFuncSetAttribute((const void*)dgm_kernel,
                        hipFuncAttributeMaxDynamicSharedMemorySize, LDS_BYTES);
    dgm_kernel<<<B / MTILE, NTHREADS, LDS_BYTES, stream>>>(X, W_in, b_in, W_out, b_out, ws, out);
}